// Round 3
// baseline (326.122 us; speedup 1.0000x reference)
//
#include <hip/hip_runtime.h>

#define BSZ   32
#define SEQ   64
#define HID   256
#define G4    1024
#define NSTEP 64

typedef unsigned long long u64;
typedef unsigned int       u32;

__device__ __forceinline__ float sigmoidf_(float v) { return 1.f / (1.f + __expf(-v)); }

// ---------------------------------------------------------------------------
// Kernel 1: context[b,j] = sum_s softmax_s(x @ Wa_x)[b,s,j] * x[b,s,j]
// (ht/ct/ba rows of Wa are constant along the softmax axis -> cancel exactly.)
// grid: 32 b * 16 jt = 512 blocks; block 256 threads.
// Phase 1: logits L[64s, 16j] = X @ Wa[:,16], x staged in LDS k-tiles
//   (coalesced), Wa read as lane-broadcast float4 (16KB slice, L1-resident).
//   thread = (s in 64) x (c in 4), owns 4 j columns.
// Phase 2: softmax over s + weighted sum, thread = (j in 16) x (sp in 16),
//   shfl_xor(1,2,4,8) reduces the 16 sp lanes.
// ---------------------------------------------------------------------------
__global__ __launch_bounds__(256) void k_context(
    const float* __restrict__ x, const float* __restrict__ Wa,
    float* __restrict__ ctx)
{
  const int b  = blockIdx.x >> 4;
  const int jt = blockIdx.x & 15;
  const int tid = threadIdx.x;
  const float* xb = x + (size_t)b * SEQ * HID;

  __shared__ __align__(16) float xs[64][68];   // k-tile: 64 s x 64 k (+pad)
  __shared__ __align__(16) float Ls[64][20];   // logits: 64 s x 16 j (+pad)

  // ---- phase 1: logits ----
  const int s  = tid >> 2;
  const int c  = tid & 3;
  const int jb = jt * 16 + c * 4;

  float a0 = 0.f, a1 = 0.f, a2 = 0.f, a3 = 0.f;
  for (int kt = 0; kt < 4; ++kt) {
    __syncthreads();   // protect xs against previous tile's readers
#pragma unroll
    for (int i = 0; i < 4; ++i) {
      const int col = i * 16 + c * 4;
      *(float4*)&xs[s][col] = *(const float4*)(xb + s * HID + kt * 64 + col);
    }
    __syncthreads();
#pragma unroll
    for (int k4 = 0; k4 < 16; ++k4) {
      const float4 xv = *(const float4*)&xs[s][k4 * 4];
#pragma unroll
      for (int e = 0; e < 4; ++e) {
        const float xe = (e == 0) ? xv.x : (e == 1) ? xv.y : (e == 2) ? xv.z : xv.w;
        const float4 wa = *(const float4*)(Wa + (size_t)(kt * 64 + k4 * 4 + e) * HID + jb);
        a0 += xe * wa.x; a1 += xe * wa.y; a2 += xe * wa.z; a3 += xe * wa.w;
      }
    }
  }
  Ls[s][c * 4 + 0] = a0; Ls[s][c * 4 + 1] = a1;
  Ls[s][c * 4 + 2] = a2; Ls[s][c * 4 + 3] = a3;
  __syncthreads();

  // ---- phase 2: softmax over s, ctx = sum alpha * x ----
  const int j  = tid >> 4;   // 0..15
  const int sp = tid & 15;   // 0..15
  float lg[4];
#pragma unroll
  for (int ss = 0; ss < 4; ++ss) lg[ss] = Ls[ss * 16 + sp][j];

  float m = fmaxf(fmaxf(lg[0], lg[1]), fmaxf(lg[2], lg[3]));
  m = fmaxf(m, __shfl_xor(m, 1));
  m = fmaxf(m, __shfl_xor(m, 2));
  m = fmaxf(m, __shfl_xor(m, 4));
  m = fmaxf(m, __shfl_xor(m, 8));

  float e[4], sm = 0.f;
#pragma unroll
  for (int ss = 0; ss < 4; ++ss) { e[ss] = __expf(lg[ss] - m); sm += e[ss]; }
  sm += __shfl_xor(sm, 1);
  sm += __shfl_xor(sm, 2);
  sm += __shfl_xor(sm, 4);
  sm += __shfl_xor(sm, 8);
  const float inv = 1.f / sm;

  const int jch = jt * 16 + j;
  float cx = 0.f;
#pragma unroll
  for (int ss = 0; ss < 4; ++ss)
    cx += e[ss] * xb[(ss * 16 + sp) * HID + jch];
  cx *= inv;
  cx += __shfl_xor(cx, 1);
  cx += __shfl_xor(cx, 2);
  cx += __shfl_xor(cx, 4);
  cx += __shfl_xor(cx, 8);

  if (sp == 0) ctx[b * HID + jch] = cx;
}

// ---------------------------------------------------------------------------
// Kernel 2: 64 sequential LSTM steps. grid: 32 b * 16 q = 512 blocks (2/CU).
// Block (b,q) owns hidden j in [q*16, q*16+16) = 64 Wh columns.
// Wave wv owns hidden quad j0 = q*16 + wv*4. Lane = gate*16 + kq
//   (gate 0..3 = i,f,g,o ; kq 0..15 = k-slice of 16).
// Thread registers: wr[64] = 4 cols x 16 k of Wh (asm-pinned; 64 floats fits
//   the RA comfortably at ~110 VGPR total -- R2's 128-float pin spilled).
// Per step: poll tagged ht -> LDS -> 1 barrier -> 64 reg-FMAs ->
//   kq shfl-reduce (xor 1,2,4,8) -> gate gather (xor 16,32) -> lane0 of each
//   wave does the pointwise + 4 tagged publishes.
// ht exchange: tagged 8B words {f32 hi | step-tag lo} in d_ws, relaxed
// agent-scope atomics, parity double-buffer. 0xAA poison never matches 1..64.
// ---------------------------------------------------------------------------
__global__ __launch_bounds__(256, 2) void k_recurrent(
    const float* __restrict__ Wi, const float* __restrict__ Wh,
    const float* __restrict__ bias, const float* __restrict__ Wf,
    const float* __restrict__ bf, const float* __restrict__ ctx,
    u64* __restrict__ tht, float* __restrict__ out)
{
  const int b    = blockIdx.x >> 4;   // 0..31
  const int q    = blockIdx.x & 15;   // 0..15 (same-q siblings share Wh slice/XCD)
  const int tid  = threadIdx.x;
  const int lane = tid & 63;
  const int wv   = tid >> 6;          // 0..3
  const int kq   = lane & 15;         // k-slice
  const int gate = lane >> 4;         // 0..3
  const int j0   = q * 16 + wv * 4;   // this wave's hidden quad
  const int col0 = gate * HID + j0;

  __shared__ __align__(16) float hs[2][16][20];
  __shared__ float red[4];

  // ---- Wh slice -> 64 VGPRs, pinned ----
  float wr[64];
#pragma unroll
  for (int kk = 0; kk < 16; ++kk) {
    const float4 w4 = *(const float4*)(Wh + (size_t)(kq * 16 + kk) * G4 + col0);
    wr[kk * 4 + 0] = w4.x; wr[kk * 4 + 1] = w4.y;
    wr[kk * 4 + 2] = w4.z; wr[kk * 4 + 3] = w4.w;
  }
#pragma unroll
  for (int i = 0; i < 64; i += 4)
    asm volatile("" : "+v"(wr[i]), "+v"(wr[i + 1]), "+v"(wr[i + 2]), "+v"(wr[i + 3]));

  // ---- stage ctx; Gc = ctx @ Wi + bias (seeded in kq==0 lanes) ----
  hs[0][tid >> 4][tid & 15] = ctx[b * HID + tid];
  __syncthreads();

  float gx = 0.f, gy = 0.f, gz = 0.f, gw = 0.f;
#pragma unroll 4
  for (int kk = 0; kk < 16; ++kk) {
    const float4 w4 = *(const float4*)(Wi + (size_t)(kq * 16 + kk) * G4 + col0);
    const float h = hs[0][kq][kk];
    gx += h * w4.x; gy += h * w4.y; gz += h * w4.z; gw += h * w4.w;
  }
#pragma unroll
  for (int mk = 1; mk < 16; mk <<= 1) {
    gx += __shfl_xor(gx, mk); gy += __shfl_xor(gy, mk);
    gz += __shfl_xor(gz, mk); gw += __shfl_xor(gw, mk);
  }
  float gcx, gcy, gcz, gcw;
  if (kq == 0) {
    const float4 bb = *(const float4*)(bias + col0);
    gcx = gx + bb.x; gcy = gy + bb.y; gcz = gz + bb.z; gcw = gw + bb.w;
  } else {
    gcx = gcy = gcz = gcw = 0.f;   // exactly one seed per kq-reduction
  }
  __syncthreads();                  // Gc reads done before hs[0] is zeroed
  hs[0][tid >> 4][tid & 15] = 0.f;  // h0 = 0
  float c0 = 0.f, c1 = 0.f, c2 = 0.f, c3 = 0.f;  // c state (lane 0 of each wave)
  __syncthreads();

  for (int t = 0; t < NSTEP; ++t) {
    const int rb = t & 1;
    const int wb = (t + 1) & 1;

    if (t > 0) {
      const u64* pp = tht + (size_t)rb * BSZ * HID + (size_t)b * HID + tid;
      u64 pk;
      do {
        pk = __hip_atomic_load(pp, __ATOMIC_RELAXED, __HIP_MEMORY_SCOPE_AGENT);
      } while ((u32)pk != (u32)t);
      hs[rb][tid >> 4][tid & 15] = __uint_as_float((u32)(pk >> 32));
      __syncthreads();
    }

    // 4 cols x 16 k, Wh from pinned regs
    float ax = gcx, ay = gcy, az = gcz, aw = gcw;
#pragma unroll
    for (int k4 = 0; k4 < 4; ++k4) {
      const float4 h4 = *(const float4*)&hs[rb][kq][k4 * 4];
      const int bs = k4 * 16;
      ax += h4.x * wr[bs +  0]; ay += h4.x * wr[bs +  1];
      az += h4.x * wr[bs +  2]; aw += h4.x * wr[bs +  3];
      ax += h4.y * wr[bs +  4]; ay += h4.y * wr[bs +  5];
      az += h4.y * wr[bs +  6]; aw += h4.y * wr[bs +  7];
      ax += h4.z * wr[bs +  8]; ay += h4.z * wr[bs +  9];
      az += h4.z * wr[bs + 10]; aw += h4.z * wr[bs + 11];
      ax += h4.w * wr[bs + 12]; ay += h4.w * wr[bs + 13];
      az += h4.w * wr[bs + 14]; aw += h4.w * wr[bs + 15];
    }
    // reduce over 16 kq partners (all lanes end with the sum)
#pragma unroll
    for (int mk = 1; mk < 16; mk <<= 1) {
      ax += __shfl_xor(ax, mk); ay += __shfl_xor(ay, mk);
      az += __shfl_xor(az, mk); aw += __shfl_xor(aw, mk);
    }
    // gather the 4 gates: lane bits 4,5 select gate; for gate==0 lanes
    // own=i, ^16=f, ^32=g, ^48=o
    const float fx = __shfl_xor(ax, 16), fy = __shfl_xor(ay, 16),
                fz = __shfl_xor(az, 16), fw = __shfl_xor(aw, 16);
    const float gx2 = __shfl_xor(ax, 32), gy2 = __shfl_xor(ay, 32),
                gz2 = __shfl_xor(az, 32), gw2 = __shfl_xor(aw, 32);
    const float ox = __shfl_xor(fx, 32), oy = __shfl_xor(fy, 32),
                oz = __shfl_xor(fz, 32), ow = __shfl_xor(fw, 32);

    if (lane == 0) {
      const float i0 = sigmoidf_(ax),  i1 = sigmoidf_(ay),
                  i2 = sigmoidf_(az),  i3 = sigmoidf_(aw);
      const float f0 = sigmoidf_(fx),  f1 = sigmoidf_(fy),
                  f2 = sigmoidf_(fz),  f3 = sigmoidf_(fw);
      const float g0 = tanhf(gx2),     g1 = tanhf(gy2),
                  g2 = tanhf(gz2),     g3 = tanhf(gw2);
      const float o0 = sigmoidf_(ox),  o1 = sigmoidf_(oy),
                  o2 = sigmoidf_(oz),  o3 = sigmoidf_(ow);
      c0 = f0 * c0 + i0 * g0;  c1 = f1 * c1 + i1 * g1;
      c2 = f2 * c2 + i2 * g2;  c3 = f3 * c3 + i3 * g3;
      const float h0v = o0 * tanhf(c0), h1v = o1 * tanhf(c1);
      const float h2v = o2 * tanhf(c2), h3v = o3 * tanhf(c3);
      u64* dst = tht + (size_t)wb * BSZ * HID + (size_t)b * HID + j0;
      const u64 tg = (u64)(u32)(t + 1);
      __hip_atomic_store(dst + 0, (((u64)__float_as_uint(h0v)) << 32) | tg,
                         __ATOMIC_RELAXED, __HIP_MEMORY_SCOPE_AGENT);
      __hip_atomic_store(dst + 1, (((u64)__float_as_uint(h1v)) << 32) | tg,
                         __ATOMIC_RELAXED, __HIP_MEMORY_SCOPE_AGENT);
      __hip_atomic_store(dst + 2, (((u64)__float_as_uint(h2v)) << 32) | tg,
                         __ATOMIC_RELAXED, __HIP_MEMORY_SCOPE_AGENT);
      __hip_atomic_store(dst + 3, (((u64)__float_as_uint(h3v)) << 32) | tg,
                         __ATOMIC_RELAXED, __HIP_MEMORY_SCOPE_AGENT);
    }
    // no trailing barrier: t+2's overwrite of this parity slot requires every
    // block to have published t+1, which happens only after its post-stage
    // barrier for t -- i.e. after all reads of t completed.
  }

  // ---- epilogue: out[b] = ht64 @ Wf + bf (q==0 sibling only) ----
  if (q == 0) {
    const u64* pp = tht + /*parity 0*/ (size_t)b * HID + tid;
    u64 pk;
    do {
      pk = __hip_atomic_load(pp, __ATOMIC_RELAXED, __HIP_MEMORY_SCOPE_AGENT);
    } while ((u32)pk != (u32)NSTEP);
    const float hv = __uint_as_float((u32)(pk >> 32));
    float prod = hv * Wf[tid];
#pragma unroll
    for (int mk = 1; mk < 64; mk <<= 1) prod += __shfl_xor(prod, mk);
    if (lane == 0) red[wv] = prod;
    __syncthreads();
    if (tid == 0) out[b] = red[0] + red[1] + red[2] + red[3] + bf[0];
  }
}

// ---------------------------------------------------------------------------
extern "C" void kernel_launch(void* const* d_in, const int* in_sizes, int n_in,
                              void* d_out, int out_size, void* d_ws, size_t ws_size,
                              hipStream_t stream)
{
  const float* x  = (const float*)d_in[0];
  const float* Wa = (const float*)d_in[1];
  // d_in[2] = ba: unused — constant along softmax axis, cancels exactly
  const float* Wi = (const float*)d_in[3];
  const float* Wh = (const float*)d_in[4];
  const float* bi = (const float*)d_in[5];
  const float* Wf = (const float*)d_in[6];
  const float* bf = (const float*)d_in[7];
  float* out = (float*)d_out;

  // ws layout: [0,32KB) fp32 context; [32KB, 32KB+128KB) tagged ht (2 bufs)
  float* ctx = (float*)d_ws;
  u64*   tht = (u64*)((char*)d_ws + 32 * 1024);

  hipLaunchKernelGGL(k_context,   dim3(BSZ * 16), dim3(256), 0, stream, x, Wa, ctx);
  hipLaunchKernelGGL(k_recurrent, dim3(BSZ * 16), dim3(256), 0, stream,
                     Wi, Wh, bi, Wf, bf, ctx, tht, out);
}

// Round 4
// 235.399 us; speedup vs baseline: 1.3854x; 1.3854x over previous
//
#include <hip/hip_runtime.h>

#define BSZ   32
#define SEQ   64
#define HID   256
#define G4    1024
#define NSTEP 64
#define QB    8      // blocks per batch
#define JB    32     // hidden units per block

typedef unsigned long long u64;
typedef unsigned int       u32;

__device__ __forceinline__ float sigmoidf_(float v) { return 1.f / (1.f + __expf(-v)); }

// ---------------------------------------------------------------------------
// Single fused kernel. grid = 32 b x 8 q = 256 blocks (1/CU, 130KB LDS each).
// Block (b,q) owns hidden j in [q*32, q*32+32) => 128 Wh columns, held in LDS
// gate-interleaved: whs[k][jj*4+gate]  (one ds_read_b128 = 4 gates of one j).
//
// Phases: A) stage x[b] (64KB) + Wa slice (32KB) in LDS arena -> logits ->
//            softmax over s -> ctx slice -> publish tagged (tag=1)
//         B) stage Wh slice into arena (overwrites A), poll full ctx,
//            Gc = ctx@Wi + bias (global Wi, one-time)
//         C) 64 steps: poll tagged ht -> LDS -> b128 MAC vs LDS-Wh ->
//            kq shfl-reduce -> pointwise on kq==0 lanes -> tagged publish.
// Sync: tagged 8B words {f32 hi | tag lo}, relaxed agent-scope atomics,
// parity double-buffer for ht. 0xAA ws-poison never matches tags.
// ---------------------------------------------------------------------------
__global__ __launch_bounds__(256, 1) void k_fused(
    const float* __restrict__ x, const float* __restrict__ Wa,
    const float* __restrict__ Wi, const float* __restrict__ Wh,
    const float* __restrict__ bias, const float* __restrict__ Wf,
    const float* __restrict__ bf,
    u64* __restrict__ tht, u64* __restrict__ ctxT, float* __restrict__ out)
{
  const int b    = blockIdx.x >> 3;
  const int q    = blockIdx.x & 7;
  const int tid  = threadIdx.x;
  const int lane = tid & 63;
  const int wv   = tid >> 6;

  // step-phase thread map: 1 j per thread, k-slice of 32
  const int jj = tid >> 3;        // 0..31 local hidden
  const int kq = tid & 7;         // 0..7  k-slice
  const int qj = q * JB + jj;     // global hidden index

  __shared__ __align__(16) float arena[256 * 128];  // 128KB multi-use
  __shared__ __align__(16) float hs[2][8][36];      // [parity][kq][32+pad]
  __shared__ float red[4];

  const float* xb = x + (size_t)b * SEQ * HID;

  // =================== phase A: context slice ===================
  // arena: xs[64][260] @0 ; was[256][32] @16640 ; Ls[64][33] @24832
#pragma unroll
  for (int it = 0; it < 16; ++it) {           // stage x[b] (row-pad 260)
    const int g = it * 1024 + tid * 4;
    const int s = g >> 8, k = g & 255;
    *(float4*)&arena[s * 260 + k] = *(const float4*)(xb + g);
  }
#pragma unroll
  for (int it = 0; it < 8; ++it) {            // stage Wa[:, q*32..+32)
    const int idx = it * 256 + tid;
    const int k = idx >> 3, cq = idx & 7;
    *(float4*)&arena[16640 + k * 32 + cq * 4] =
        *(const float4*)(Wa + (size_t)k * HID + q * JB + cq * 4);
  }
  __syncthreads();

  {  // logits L[s][jl] = sum_k x[s][k] * Wa[k][q*32+jl]
    const int ts = tid >> 2, tc = tid & 3;    // 64 s x (8 j per thread)
    float l0 = 0.f, l1 = 0.f, l2 = 0.f, l3 = 0.f,
          l4 = 0.f, l5 = 0.f, l6 = 0.f, l7 = 0.f;
    const float* xrow = &arena[ts * 260];
    const float* wab  = &arena[16640 + tc * 8];
    for (int k4 = 0; k4 < 64; ++k4) {
      const float4 xv = *(const float4*)&xrow[k4 * 4];
#define LSTEP(XE, KO)                                                        \
      { const float4 wa = *(const float4*)&wab[(k4 * 4 + KO) * 32];          \
        const float4 wb2 = *(const float4*)&wab[(k4 * 4 + KO) * 32 + 4];     \
        l0 += (XE) * wa.x;  l1 += (XE) * wa.y;  l2 += (XE) * wa.z;           \
        l3 += (XE) * wa.w;  l4 += (XE) * wb2.x; l5 += (XE) * wb2.y;          \
        l6 += (XE) * wb2.z; l7 += (XE) * wb2.w; }
      LSTEP(xv.x, 0) LSTEP(xv.y, 1) LSTEP(xv.z, 2) LSTEP(xv.w, 3)
#undef LSTEP
    }
    float* lrow = &arena[24832 + ts * 33 + tc * 8];
    lrow[0] = l0; lrow[1] = l1; lrow[2] = l2; lrow[3] = l3;
    lrow[4] = l4; lrow[5] = l5; lrow[6] = l6; lrow[7] = l7;
  }
  __syncthreads();

  {  // softmax over s (shift-invariance: ht/ct/ba terms cancel) + ctx
    const int jx = tid >> 3, sp = tid & 7;    // 32 j x (8 s per thread)
    float lg[8];
#pragma unroll
    for (int e = 0; e < 8; ++e) lg[e] = arena[24832 + (sp * 8 + e) * 33 + jx];
    float m = lg[0];
#pragma unroll
    for (int e = 1; e < 8; ++e) m = fmaxf(m, lg[e]);
    m = fmaxf(m, __shfl_xor(m, 1));
    m = fmaxf(m, __shfl_xor(m, 2));
    m = fmaxf(m, __shfl_xor(m, 4));
    float ex[8], sm = 0.f;
#pragma unroll
    for (int e = 0; e < 8; ++e) { ex[e] = __expf(lg[e] - m); sm += ex[e]; }
    sm += __shfl_xor(sm, 1);
    sm += __shfl_xor(sm, 2);
    sm += __shfl_xor(sm, 4);
    const float inv = 1.f / sm;
    const int gj = q * JB + jx;
    float cx = 0.f;
#pragma unroll
    for (int e = 0; e < 8; ++e) cx += ex[e] * arena[(sp * 8 + e) * 260 + gj];
    cx *= inv;
    cx += __shfl_xor(cx, 1);
    cx += __shfl_xor(cx, 2);
    cx += __shfl_xor(cx, 4);
    if (sp == 0)
      __hip_atomic_store(ctxT + b * HID + gj,
                         (((u64)__float_as_uint(cx)) << 32) | 1ull,
                         __ATOMIC_RELAXED, __HIP_MEMORY_SCOPE_AGENT);
  }
  __syncthreads();   // all arena (xs/Ls) reads done -> arena reusable

  // =================== phase B: Wh -> LDS, ctx poll, Gc ===================
  // whs[k][c] = arena[k*128 + c], c = jj*4 + gate
#pragma unroll
  for (int it = 0; it < 32; ++it) {
    const int k  = it * 8 + (tid >> 5);
    const int g  = (tid >> 3) & 3;
    const int jq = tid & 7;
    const float4 w4 = *(const float4*)(Wh + (size_t)k * G4 + g * HID + q * JB + jq * 4);
    float* dst = &arena[k * 128 + g];
    dst[(jq * 4 + 0) * 4] = w4.x;
    dst[(jq * 4 + 1) * 4] = w4.y;
    dst[(jq * 4 + 2) * 4] = w4.z;
    dst[(jq * 4 + 3) * 4] = w4.w;
  }
  {  // poll full ctx (8 publisher blocks) -> hs[0]
    const u64* pp = ctxT + b * HID + tid;
    u64 pk;
    do {
      pk = __hip_atomic_load(pp, __ATOMIC_RELAXED, __HIP_MEMORY_SCOPE_AGENT);
    } while ((u32)pk != 1u);
    hs[0][tid >> 5][tid & 31] = __uint_as_float((u32)(pk >> 32));
  }
  __syncthreads();   // hs(ctx) + whs both ready

  // Gc = ctx @ Wi + bias for (jj, 4 gates); partial over k-slice, kq-reduce
  float gcx = 0.f, gcy = 0.f, gcz = 0.f, gcw = 0.f;
  {
    const float* wik = Wi + qj;
#pragma unroll 4
    for (int ks = 0; ks < 32; ++ks) {
      const int k = kq * 32 + ks;
      const float h = hs[0][kq][ks];
      gcx += h * wik[(size_t)k * G4 + 0 * HID];
      gcy += h * wik[(size_t)k * G4 + 1 * HID];
      gcz += h * wik[(size_t)k * G4 + 2 * HID];
      gcw += h * wik[(size_t)k * G4 + 3 * HID];
    }
#pragma unroll
    for (int mk = 1; mk < 8; mk <<= 1) {
      gcx += __shfl_xor(gcx, mk); gcy += __shfl_xor(gcy, mk);
      gcz += __shfl_xor(gcz, mk); gcw += __shfl_xor(gcw, mk);
    }
    if (kq == 0) {
      gcx += bias[0 * HID + qj]; gcy += bias[1 * HID + qj];
      gcz += bias[2 * HID + qj]; gcw += bias[3 * HID + qj];
    } else {
      gcx = gcy = gcz = gcw = 0.f;   // exactly one seed per kq-reduction
    }
  }
  __syncthreads();                   // Gc's hs[0] reads complete
  hs[0][tid >> 5][tid & 31] = 0.f;   // h0 = 0
  __syncthreads();
  float cst = 0.f;                   // c state (kq==0 lanes)

  // =================== phase C: 64 recurrent steps ===================
  for (int t = 0; t < NSTEP; ++t) {
    const int rb = t & 1;
    const int wb = (t + 1) & 1;

    if (t > 0) {
      const u64* pp = tht + (size_t)rb * BSZ * HID + (size_t)b * HID + tid;
      u64 pk;
      do {
        pk = __hip_atomic_load(pp, __ATOMIC_RELAXED, __HIP_MEMORY_SCOPE_AGENT);
      } while ((u32)pk != (u32)t);
      hs[rb][tid >> 5][tid & 31] = __uint_as_float((u32)(pk >> 32));
      __syncthreads();
    }

    // gates[jj, 4 gates] partial: 32 k from LDS-Wh (b128 = 4 gates of one j)
    float ax = gcx, ay = gcy, az = gcz, aw = gcw;
#pragma unroll
    for (int k4 = 0; k4 < 8; ++k4) {
      const float4 h4 = *(const float4*)&hs[rb][kq][k4 * 4];
      const int kb = (kq * 32 + k4 * 4) * 128 + jj * 4;
      const float4 w0 = *(const float4*)&arena[kb];
      const float4 w1 = *(const float4*)&arena[kb + 128];
      const float4 w2 = *(const float4*)&arena[kb + 256];
      const float4 w3 = *(const float4*)&arena[kb + 384];
      ax += h4.x * w0.x; ay += h4.x * w0.y; az += h4.x * w0.z; aw += h4.x * w0.w;
      ax += h4.y * w1.x; ay += h4.y * w1.y; az += h4.y * w1.z; aw += h4.y * w1.w;
      ax += h4.z * w2.x; ay += h4.z * w2.y; az += h4.z * w2.z; aw += h4.z * w2.w;
      ax += h4.w * w3.x; ay += h4.w * w3.y; az += h4.w * w3.z; aw += h4.w * w3.w;
    }
#pragma unroll
    for (int mk = 1; mk < 8; mk <<= 1) {
      ax += __shfl_xor(ax, mk); ay += __shfl_xor(ay, mk);
      az += __shfl_xor(az, mk); aw += __shfl_xor(aw, mk);
    }

    if (kq == 0) {   // ax=i, ay=f, az=g, aw=o for hidden qj
      const float ig = sigmoidf_(ax);
      const float fg = sigmoidf_(ay);
      const float gg = tanhf(az);
      const float og = sigmoidf_(aw);
      cst = fg * cst + ig * gg;
      const float hv = og * tanhf(cst);
      __hip_atomic_store(tht + (size_t)wb * BSZ * HID + (size_t)b * HID + qj,
                         (((u64)__float_as_uint(hv)) << 32) | (u64)(u32)(t + 1),
                         __ATOMIC_RELAXED, __HIP_MEMORY_SCOPE_AGENT);
    }
    // no trailing barrier: next stage targets the other parity buffer; a t+2
    // overwrite of this slot requires all siblings past their t-read barrier.
  }

  // =================== epilogue: out[b] = ht @ Wf + bf ===================
  if (q == 0) {
    const u64* pp = tht + /*parity 0*/ (size_t)b * HID + tid;
    u64 pk;
    do {
      pk = __hip_atomic_load(pp, __ATOMIC_RELAXED, __HIP_MEMORY_SCOPE_AGENT);
    } while ((u32)pk != (u32)NSTEP);
    const float hv = __uint_as_float((u32)(pk >> 32));
    float prod = hv * Wf[tid];
#pragma unroll
    for (int mk = 1; mk < 64; mk <<= 1) prod += __shfl_xor(prod, mk);
    if (lane == 0) red[wv] = prod;
    __syncthreads();
    if (tid == 0) out[b] = red[0] + red[1] + red[2] + red[3] + bf[0];
  }
}

// ---------------------------------------------------------------------------
extern "C" void kernel_launch(void* const* d_in, const int* in_sizes, int n_in,
                              void* d_out, int out_size, void* d_ws, size_t ws_size,
                              hipStream_t stream)
{
  const float* x  = (const float*)d_in[0];
  const float* Wa = (const float*)d_in[1];
  // d_in[2] = ba: unused — constant along softmax axis, cancels exactly
  const float* Wi = (const float*)d_in[3];
  const float* Wh = (const float*)d_in[4];
  const float* bi = (const float*)d_in[5];
  const float* Wf = (const float*)d_in[6];
  const float* bf = (const float*)d_in[7];
  float* out = (float*)d_out;

  // ws: [0,128KB) tagged ht (2 parity bufs); [128KB,192KB) tagged ctx
  u64* tht  = (u64*)d_ws;
  u64* ctxT = (u64*)((char*)d_ws + 2 * BSZ * HID * sizeof(u64));

  hipLaunchKernelGGL(k_fused, dim3(BSZ * QB), dim3(256), 0, stream,
                     x, Wa, Wi, Wh, bi, Wf, bf, tht, ctxT, out);
}

// Round 5
// 194.221 us; speedup vs baseline: 1.6791x; 1.2120x over previous
//
#include <hip/hip_runtime.h>

#define BSZ   32
#define SEQ   64
#define HID   256
#define G4    1024
#define NSTEP 64
#define QB    8      // blocks per batch
#define JB    32     // hidden units per block

typedef unsigned long long u64;
typedef unsigned int       u32;

__device__ __forceinline__ float sigmoidf_(float v) { return 1.f / (1.f + __expf(-v)); }

// ---------------------------------------------------------------------------
// Single fused kernel. grid = 32 b x 8 q = 256 blocks (1/CU, ~138KB LDS).
// Block (b,q) owns hidden j in [q*32, q*32+32) => 128 W columns.
// LDS W tile layout: arena[k][g*32 + j_local]  (gate-blocked, = global layout
// => staging is a straight float4 copy, coalesced + conflict-free).
//
// Step thread map: jj = tid&31 (hidden), kq = tid>>5 (k-slice of 32 = source
// block). Every LDS access is contiguous per 16-lane phase => 2-way max =
// conflict-free (m136). MAC = 128 b32 W-reads + 8 b128 h-broadcasts + 128 FMA.
// kq-reduction via parity-double-buffered gred[2][8][32]f4 + ONE barrier/step;
// threads 0..31 reduce, do pointwise, publish tagged h.
// h staging is half-wave-local (thread reads only hs words its own half-wave
// staged; same-wave LDS ops are program-ordered) => no post-stage barrier.
// Sync: tagged 8B words {f32 hi | tag lo}, relaxed agent-scope atomics,
// parity double-buffer for tht. 0xAA ws-poison never matches tags.
// ---------------------------------------------------------------------------
__global__ __launch_bounds__(256, 1) void k_fused(
    const float* __restrict__ x, const float* __restrict__ Wa,
    const float* __restrict__ Wi, const float* __restrict__ Wh,
    const float* __restrict__ bias, const float* __restrict__ Wf,
    const float* __restrict__ bf,
    u64* __restrict__ tht, u64* __restrict__ ctxT, float* __restrict__ out)
{
  const int b    = blockIdx.x >> 3;
  const int q    = blockIdx.x & 7;
  const int tid  = threadIdx.x;
  const int lane = tid & 63;
  const int wv   = tid >> 6;
  const int jj   = tid & 31;      // hidden-local (step phases)
  const int kq   = tid >> 5;      // k-slice / source block (0..7)
  const int qj   = q * JB + jj;   // global hidden index

  __shared__ __align__(16) float arena[32768];        // 128KB: x/Wa/L, then W tile
  __shared__ __align__(16) float hs[256];             // staged h (half-wave-local)
  __shared__ __align__(16) float cs[256];             // staged ctx
  __shared__ __align__(16) float gred[2][8][JB * 4];  // [par][kq][jj*4+g] partials
  __shared__ float red[4];

  const float* xb = x + (size_t)b * SEQ * HID;

  // =================== phase A: context slice (verified R4) ===================
  // arena: xs[64][260] @0 ; was[256][32] @16640 ; Ls[64][33] @24832
#pragma unroll
  for (int it = 0; it < 16; ++it) {           // stage x[b] (row-pad 260)
    const int g = it * 1024 + tid * 4;
    const int s = g >> 8, k = g & 255;
    *(float4*)&arena[s * 260 + k] = *(const float4*)(xb + g);
  }
#pragma unroll
  for (int it = 0; it < 8; ++it) {            // stage Wa[:, q*32..+32)
    const int idx = it * 256 + tid;
    const int k = idx >> 3, cq = idx & 7;
    *(float4*)&arena[16640 + k * 32 + cq * 4] =
        *(const float4*)(Wa + (size_t)k * HID + q * JB + cq * 4);
  }
  __syncthreads();

  {  // logits L[s][jl] = sum_k x[s][k] * Wa[k][q*32+jl]
    const int ts = tid >> 2, tc = tid & 3;
    float l0 = 0.f, l1 = 0.f, l2 = 0.f, l3 = 0.f,
          l4 = 0.f, l5 = 0.f, l6 = 0.f, l7 = 0.f;
    const float* xrow = &arena[ts * 260];
    const float* wab  = &arena[16640 + tc * 8];
    for (int k4 = 0; k4 < 64; ++k4) {
      const float4 xv = *(const float4*)&xrow[k4 * 4];
#define LSTEP(XE, KO)                                                        \
      { const float4 wa = *(const float4*)&wab[(k4 * 4 + KO) * 32];          \
        const float4 wb2 = *(const float4*)&wab[(k4 * 4 + KO) * 32 + 4];     \
        l0 += (XE) * wa.x;  l1 += (XE) * wa.y;  l2 += (XE) * wa.z;           \
        l3 += (XE) * wa.w;  l4 += (XE) * wb2.x; l5 += (XE) * wb2.y;          \
        l6 += (XE) * wb2.z; l7 += (XE) * wb2.w; }
      LSTEP(xv.x, 0) LSTEP(xv.y, 1) LSTEP(xv.z, 2) LSTEP(xv.w, 3)
#undef LSTEP
    }
    float* lrow = &arena[24832 + ts * 33 + tc * 8];
    lrow[0] = l0; lrow[1] = l1; lrow[2] = l2; lrow[3] = l3;
    lrow[4] = l4; lrow[5] = l5; lrow[6] = l6; lrow[7] = l7;
  }
  __syncthreads();

  {  // softmax over s (shift-invariance: ht/ct/ba terms cancel) + ctx publish
    const int jx = tid >> 3, sp = tid & 7;
    float lg[8];
#pragma unroll
    for (int e = 0; e < 8; ++e) lg[e] = arena[24832 + (sp * 8 + e) * 33 + jx];
    float m = lg[0];
#pragma unroll
    for (int e = 1; e < 8; ++e) m = fmaxf(m, lg[e]);
    m = fmaxf(m, __shfl_xor(m, 1));
    m = fmaxf(m, __shfl_xor(m, 2));
    m = fmaxf(m, __shfl_xor(m, 4));
    float ex[8], sm = 0.f;
#pragma unroll
    for (int e = 0; e < 8; ++e) { ex[e] = __expf(lg[e] - m); sm += ex[e]; }
    sm += __shfl_xor(sm, 1);
    sm += __shfl_xor(sm, 2);
    sm += __shfl_xor(sm, 4);
    const float inv = 1.f / sm;
    const int gj = q * JB + jx;
    float cx = 0.f;
#pragma unroll
    for (int e = 0; e < 8; ++e) cx += ex[e] * arena[(sp * 8 + e) * 260 + gj];
    cx *= inv;
    cx += __shfl_xor(cx, 1);
    cx += __shfl_xor(cx, 2);
    cx += __shfl_xor(cx, 4);
    if (sp == 0)
      __hip_atomic_store(ctxT + b * HID + gj,
                         (((u64)__float_as_uint(cx)) << 32) | 1ull,
                         __ATOMIC_RELAXED, __HIP_MEMORY_SCOPE_AGENT);
  }
  __syncthreads();   // all xs/Ls reads done -> arena reusable

  // 32-k-slice MAC against the LDS W tile; every access conflict-free.
#define MAC32(HSRC, ACC)                                                     \
  _Pragma("unroll")                                                          \
  for (int ks4 = 0; ks4 < 8; ++ks4) {                                        \
    const float4 h4 = *(const float4*)&(HSRC)[kq * 32 + ks4 * 4];            \
    _Pragma("unroll")                                                        \
    for (int e = 0; e < 4; ++e) {                                            \
      const float he = (e == 0) ? h4.x : (e == 1) ? h4.y                     \
                     : (e == 2) ? h4.z : h4.w;                               \
      const float* wrow = &arena[(kq * 32 + ks4 * 4 + e) * 128];             \
      ACC.x += he * wrow[jj];                                                \
      ACC.y += he * wrow[32 + jj];                                           \
      ACC.z += he * wrow[64 + jj];                                           \
      ACC.w += he * wrow[96 + jj];                                           \
    }                                                                        \
  }

  // =================== phase B: Wi tile, ctx poll, Gc ===================
#pragma unroll
  for (int i = 0; i < 32; ++i) {              // stage Wi slice (straight copy)
    const int f = i * 256 + tid;              // float4 linear index
    const int k = f >> 5, c4 = f & 31;
    const int g = c4 >> 3, jw = c4 & 7;
    *(float4*)&arena[f * 4] =
        *(const float4*)(Wi + (size_t)k * G4 + g * HID + q * JB + jw * 4);
  }
  {  // poll full ctx (tag=1) -> cs
    const u64* pp = ctxT + b * HID + tid;
    u64 pk;
    do {
      pk = __hip_atomic_load(pp, __ATOMIC_RELAXED, __HIP_MEMORY_SCOPE_AGENT);
    } while ((u32)pk != 1u);
    cs[tid] = __uint_as_float((u32)(pk >> 32));
  }
  __syncthreads();

  float4 ac = {0.f, 0.f, 0.f, 0.f};
  MAC32(cs, ac);
  *(float4*)&gred[0][kq][jj * 4] = ac;
  __syncthreads();

  float4 gcr = {0.f, 0.f, 0.f, 0.f};          // Gc + bias (reducer registers)
  float  cst = 0.f;                           // c state  (reducer registers)
  if (tid < 32) {
#pragma unroll
    for (int k2 = 0; k2 < 8; ++k2) {
      const float4 v = *(const float4*)&gred[0][k2][tid * 4];
      gcr.x += v.x; gcr.y += v.y; gcr.z += v.z; gcr.w += v.w;
    }
    gcr.x += bias[qj];           gcr.y += bias[HID + qj];
    gcr.z += bias[2 * HID + qj]; gcr.w += bias[3 * HID + qj];
    // step 0 (h=0): gates = Gc directly; publish tag 1 early (overlaps staging)
    const float ig = sigmoidf_(gcr.x), fg0 = sigmoidf_(gcr.y);
    const float gg = tanhf(gcr.z),     og  = sigmoidf_(gcr.w);
    (void)fg0;
    cst = ig * gg;
    const float hv = og * tanhf(cst);
    __hip_atomic_store(tht + (size_t)1 * BSZ * HID + (size_t)b * HID + qj,
                       (((u64)__float_as_uint(hv)) << 32) | 1ull,
                       __ATOMIC_RELAXED, __HIP_MEMORY_SCOPE_AGENT);
  }
#pragma unroll
  for (int i = 0; i < 32; ++i) {              // stage Wh (overwrites Wi tile)
    const int f = i * 256 + tid;
    const int k = f >> 5, c4 = f & 31;
    const int g = c4 >> 3, jw = c4 & 7;
    *(float4*)&arena[f * 4] =
        *(const float4*)(Wh + (size_t)k * G4 + g * HID + q * JB + jw * 4);
  }
  __syncthreads();

  // =================== phase C: recurrent steps 1..63 ===================
  for (int t = 1; t < NSTEP; ++t) {
    const int rb = t & 1;
    {
      const u64* pp = tht + (size_t)rb * BSZ * HID + (size_t)b * HID + tid;
      u64 pk;
      do {
        pk = __hip_atomic_load(pp, __ATOMIC_RELAXED, __HIP_MEMORY_SCOPE_AGENT);
      } while ((u32)pk != (u32)t);
      hs[tid] = __uint_as_float((u32)(pk >> 32));
    }
    // hs RAW is half-wave-local (reader kq == writer kq); same-wave LDS ops
    // are program-ordered and the compiler keeps lgkmcnt for the alias.
    float4 a2 = {0.f, 0.f, 0.f, 0.f};
    MAC32(hs, a2);
    *(float4*)&gred[rb][kq][jj * 4] = a2;
    __syncthreads();

    if (tid < 32) {   // reducer for hidden jj==tid: sum 8 kq partials + Gc
      float4 s = gcr;
#pragma unroll
      for (int k2 = 0; k2 < 8; ++k2) {
        const float4 v = *(const float4*)&gred[rb][k2][tid * 4];
        s.x += v.x; s.y += v.y; s.z += v.z; s.w += v.w;
      }
      const float ig = sigmoidf_(s.x), fg = sigmoidf_(s.y);
      const float gg = tanhf(s.z),     og = sigmoidf_(s.w);
      cst = fg * cst + ig * gg;
      const float hv = og * tanhf(cst);
      __hip_atomic_store(tht + (size_t)((t + 1) & 1) * BSZ * HID
                             + (size_t)b * HID + qj,
                         (((u64)__float_as_uint(hv)) << 32) | (u64)(u32)(t + 1),
                         __ATOMIC_RELAXED, __HIP_MEMORY_SCOPE_AGENT);
    }
    // gred parity race-free: a t+2 overwrite of gred[rb] requires poll(t+2)
    // => our reducer published t+2 => its gred[rb] reads (step t) completed.
  }

  // =================== epilogue: out[b] = ht @ Wf + bf ===================
  if (q == 0) {
    const u64* pp = tht + /*parity 0*/ (size_t)b * HID + tid;
    u64 pk;
    do {
      pk = __hip_atomic_load(pp, __ATOMIC_RELAXED, __HIP_MEMORY_SCOPE_AGENT);
    } while ((u32)pk != (u32)NSTEP);
    const float hv = __uint_as_float((u32)(pk >> 32));
    float prod = hv * Wf[tid];
#pragma unroll
    for (int mk = 1; mk < 64; mk <<= 1) prod += __shfl_xor(prod, mk);
    if (lane == 0) red[wv] = prod;
    __syncthreads();
    if (tid == 0) out[b] = red[0] + red[1] + red[2] + red[3] + bf[0];
  }
#undef MAC32
}

// ---------------------------------------------------------------------------
extern "C" void kernel_launch(void* const* d_in, const int* in_sizes, int n_in,
                              void* d_out, int out_size, void* d_ws, size_t ws_size,
                              hipStream_t stream)
{
  const float* x  = (const float*)d_in[0];
  const float* Wa = (const float*)d_in[1];
  // d_in[2] = ba: unused — constant along softmax axis, cancels exactly
  const float* Wi = (const float*)d_in[3];
  const float* Wh = (const float*)d_in[4];
  const float* bi = (const float*)d_in[5];
  const float* Wf = (const float*)d_in[6];
  const float* bf = (const float*)d_in[7];
  float* out = (float*)d_out;

  // ws: [0,128KB) tagged ht (2 parity bufs); [128KB,192KB) tagged ctx
  u64* tht  = (u64*)d_ws;
  u64* ctxT = (u64*)((char*)d_ws + 2 * BSZ * HID * sizeof(u64));

  hipLaunchKernelGGL(k_fused, dim3(BSZ * QB), dim3(256), 0, stream,
                     x, Wa, Wi, Wh, bi, Wf, bf, tht, ctxT, out);
}

// Round 6
// 159.171 us; speedup vs baseline: 2.0489x; 1.2202x over previous
//
#include <hip/hip_runtime.h>

#define BSZ   32
#define SEQ   64
#define HID   256
#define G4    1024
#define NSTEP 64
#define QB    8      // blocks per batch
#define JB    32     // hidden units per block

typedef unsigned long long u64;
typedef unsigned int       u32;

__device__ __forceinline__ float sigmoidf_(float v) { return 1.f / (1.f + __expf(-v)); }

// ---------------------------------------------------------------------------
// Single fused kernel. grid = 256 = 32 b x 8 q, decoded b = idx&31, q = idx>>5
// so all 8 siblings of a batch land on ONE XCD (XCD = idx%8 = b%8): the
// tagged-word h exchange is served by that XCD's L2, not the die-level LLC.
//
// Block (b,q) owns hidden j in [q*32, q*32+32) => 128 W columns in LDS,
// layout arena[k*128 + g*32 + j] (= global layout, straight float4 staging).
//
// Step thread map: jq = tid&7 (hidden quad j=jq*4..+3), g = (tid>>3)&3 (gate),
// kq = tid>>5 (k-slice of 32). All W/gred accesses are ds_read_b128 with
// 16-lane phases spanning all 32 banks 2-way (free, m136); h reads are
// 8-lane broadcasts (free). h staging is half-wave-local (reader kq==tid>>5
// reads words written by tids kq*32..+31 = its own half-wave) => no
// post-stage barrier. One barrier per step (before the kq-reduction).
// Sync: tagged 8B words {f32 hi | tag lo}, relaxed agent-scope atomics,
// parity double-buffer for tht & gred. 0xAA ws-poison never matches tags.
// ---------------------------------------------------------------------------
__global__ __launch_bounds__(256, 1) void k_fused(
    const float* __restrict__ x, const float* __restrict__ Wa,
    const float* __restrict__ Wi, const float* __restrict__ Wh,
    const float* __restrict__ bias, const float* __restrict__ Wf,
    const float* __restrict__ bf,
    u64* __restrict__ tht, u64* __restrict__ ctxT, float* __restrict__ out)
{
  const int b    = blockIdx.x & 31;   // siblings of a batch share an XCD
  const int q    = blockIdx.x >> 5;
  const int tid  = threadIdx.x;
  const int lane = tid & 63;
  const int wv   = tid >> 6;
  const int jq   = tid & 7;           // hidden quad (j = jq*4 .. +3)
  const int g    = (tid >> 3) & 3;    // gate
  const int kq   = tid >> 5;          // k-slice (0..7), half-wave granular

  __shared__ __align__(16) float arena[32768];        // 128KB: x/Wa/L, then W tile
  __shared__ __align__(16) float hs[256];             // staged h (half-wave-local)
  __shared__ __align__(16) float cs[256];             // staged ctx
  __shared__ __align__(16) float gred[2][8][JB * 4];  // [par][kq][g*32 + j]
  __shared__ float red[4];

  const float* xb = x + (size_t)b * SEQ * HID;

  // =================== phase A: context slice (verified R4/R5) ===============
  // arena: xs[64][260] @0 ; was[256][32] @16640 ; Ls[64][33] @24832
#pragma unroll
  for (int it = 0; it < 16; ++it) {           // stage x[b] (row-pad 260)
    const int gl = it * 1024 + tid * 4;
    const int s = gl >> 8, k = gl & 255;
    *(float4*)&arena[s * 260 + k] = *(const float4*)(xb + gl);
  }
#pragma unroll
  for (int it = 0; it < 8; ++it) {            // stage Wa[:, q*32..+32)
    const int idx = it * 256 + tid;
    const int k = idx >> 3, cq = idx & 7;
    *(float4*)&arena[16640 + k * 32 + cq * 4] =
        *(const float4*)(Wa + (size_t)k * HID + q * JB + cq * 4);
  }
  __syncthreads();

  {  // logits L[s][jl] = sum_k x[s][k] * Wa[k][q*32+jl]
    const int ts = tid >> 2, tc = tid & 3;
    float l0 = 0.f, l1 = 0.f, l2 = 0.f, l3 = 0.f,
          l4 = 0.f, l5 = 0.f, l6 = 0.f, l7 = 0.f;
    const float* xrow = &arena[ts * 260];
    const float* wab  = &arena[16640 + tc * 8];
    for (int k4 = 0; k4 < 64; ++k4) {
      const float4 xv = *(const float4*)&xrow[k4 * 4];
#define LSTEP(XE, KO)                                                        \
      { const float4 wa = *(const float4*)&wab[(k4 * 4 + KO) * 32];          \
        const float4 wb2 = *(const float4*)&wab[(k4 * 4 + KO) * 32 + 4];     \
        l0 += (XE) * wa.x;  l1 += (XE) * wa.y;  l2 += (XE) * wa.z;           \
        l3 += (XE) * wa.w;  l4 += (XE) * wb2.x; l5 += (XE) * wb2.y;          \
        l6 += (XE) * wb2.z; l7 += (XE) * wb2.w; }
      LSTEP(xv.x, 0) LSTEP(xv.y, 1) LSTEP(xv.z, 2) LSTEP(xv.w, 3)
#undef LSTEP
    }
    float* lrow = &arena[24832 + ts * 33 + tc * 8];
    lrow[0] = l0; lrow[1] = l1; lrow[2] = l2; lrow[3] = l3;
    lrow[4] = l4; lrow[5] = l5; lrow[6] = l6; lrow[7] = l7;
  }
  __syncthreads();

  {  // softmax over s (shift-invariance: ht/ct/ba terms cancel) + ctx publish
    const int jx = tid >> 3, sp = tid & 7;
    float lg[8];
#pragma unroll
    for (int e = 0; e < 8; ++e) lg[e] = arena[24832 + (sp * 8 + e) * 33 + jx];
    float m = lg[0];
#pragma unroll
    for (int e = 1; e < 8; ++e) m = fmaxf(m, lg[e]);
    m = fmaxf(m, __shfl_xor(m, 1));
    m = fmaxf(m, __shfl_xor(m, 2));
    m = fmaxf(m, __shfl_xor(m, 4));
    float ex[8], sm = 0.f;
#pragma unroll
    for (int e = 0; e < 8; ++e) { ex[e] = __expf(lg[e] - m); sm += ex[e]; }
    sm += __shfl_xor(sm, 1);
    sm += __shfl_xor(sm, 2);
    sm += __shfl_xor(sm, 4);
    const float inv = 1.f / sm;
    const int gj = q * JB + jx;
    float cx = 0.f;
#pragma unroll
    for (int e = 0; e < 8; ++e) cx += ex[e] * arena[(sp * 8 + e) * 260 + gj];
    cx *= inv;
    cx += __shfl_xor(cx, 1);
    cx += __shfl_xor(cx, 2);
    cx += __shfl_xor(cx, 4);
    if (sp == 0)
      __hip_atomic_store(ctxT + b * HID + gj,
                         (((u64)__float_as_uint(cx)) << 32) | 1ull,
                         __ATOMIC_RELAXED, __HIP_MEMORY_SCOPE_AGENT);
  }
  __syncthreads();   // all xs/Ls reads done -> arena reusable

  // 32-k-slice MAC vs LDS W tile — all ds_read_b128, conflict-free.
  // ACC.e accumulates gate g of hidden j = jq*4+e.
#define MAC32(HSRC, ACC)                                                     \
  _Pragma("unroll")                                                          \
  for (int k4 = 0; k4 < 8; ++k4) {                                           \
    const float4 h4 = *(const float4*)&(HSRC)[kq * 32 + k4 * 4];             \
    const float* wp = &arena[(kq * 32 + k4 * 4) * 128 + g * 32 + jq * 4];    \
    const float4 w0 = *(const float4*)&wp[0];                                \
    const float4 w1 = *(const float4*)&wp[128];                              \
    const float4 w2 = *(const float4*)&wp[256];                              \
    const float4 w3 = *(const float4*)&wp[384];                              \
    ACC.x += h4.x * w0.x + h4.y * w1.x + h4.z * w2.x + h4.w * w3.x;          \
    ACC.y += h4.x * w0.y + h4.y * w1.y + h4.z * w2.y + h4.w * w3.y;          \
    ACC.z += h4.x * w0.z + h4.y * w1.z + h4.z * w2.z + h4.w * w3.z;          \
    ACC.w += h4.x * w0.w + h4.y * w1.w + h4.z * w2.w + h4.w * w3.w;          \
  }

  // =================== phase B: Wi tile, ctx poll, Gc ===================
#pragma unroll
  for (int i = 0; i < 32; ++i) {              // stage Wi slice (straight copy)
    const int f = i * 256 + tid;              // float4 linear index
    const int k = f >> 5, c4 = f & 31;
    const int gq = c4 >> 3, jw = c4 & 7;
    *(float4*)&arena[f * 4] =
        *(const float4*)(Wi + (size_t)k * G4 + gq * HID + q * JB + jw * 4);
  }
  {  // poll full ctx (tag=1) -> cs
    const u64* pp = ctxT + b * HID + tid;
    u64 pk;
    do {
      pk = __hip_atomic_load(pp, __ATOMIC_RELAXED, __HIP_MEMORY_SCOPE_AGENT);
    } while ((u32)pk != 1u);
    cs[tid] = __uint_as_float((u32)(pk >> 32));
  }
  __syncthreads();

  float4 ac = {0.f, 0.f, 0.f, 0.f};
  MAC32(cs, ac);
  *(float4*)&gred[0][kq][g * 32 + jq * 4] = ac;
  __syncthreads();

  float4 gcr = {0.f, 0.f, 0.f, 0.f};          // Gc + bias (reducer registers)
  float  cst = 0.f;                           // c state  (reducer registers)
  if (tid < 32) {                             // reducer for hidden j = tid
    const int qj = q * JB + tid;
#pragma unroll
    for (int k2 = 0; k2 < 8; ++k2) {
      const float* gp = &gred[0][k2][tid];
      gcr.x += gp[0]; gcr.y += gp[32]; gcr.z += gp[64]; gcr.w += gp[96];
    }
    gcr.x += bias[qj];           gcr.y += bias[HID + qj];
    gcr.z += bias[2 * HID + qj]; gcr.w += bias[3 * HID + qj];
    // step 0 (h=0): gates = Gc directly; publish tag 1 early (overlaps staging)
    const float ig = sigmoidf_(gcr.x);
    const float gg = tanhf(gcr.z), og = sigmoidf_(gcr.w);
    cst = ig * gg;
    const float hv = og * tanhf(cst);
    __hip_atomic_store(tht + (size_t)1 * BSZ * HID + (size_t)b * HID + qj,
                       (((u64)__float_as_uint(hv)) << 32) | 1ull,
                       __ATOMIC_RELAXED, __HIP_MEMORY_SCOPE_AGENT);
  }
#pragma unroll
  for (int i = 0; i < 32; ++i) {              // stage Wh (overwrites Wi tile)
    const int f = i * 256 + tid;
    const int k = f >> 5, c4 = f & 31;
    const int gq = c4 >> 3, jw = c4 & 7;
    *(float4*)&arena[f * 4] =
        *(const float4*)(Wh + (size_t)k * G4 + gq * HID + q * JB + jw * 4);
  }
  __syncthreads();

  // =================== phase C: recurrent steps 1..63 ===================
  for (int t = 1; t < NSTEP; ++t) {
    const int rb = t & 1;
    {
      const u64* pp = tht + (size_t)rb * BSZ * HID + (size_t)b * HID + tid;
      u64 pk;
      do {
        pk = __hip_atomic_load(pp, __ATOMIC_RELAXED, __HIP_MEMORY_SCOPE_AGENT);
      } while ((u32)pk != (u32)t);
      hs[tid] = __uint_as_float((u32)(pk >> 32));
    }
    // hs RAW is half-wave-local (reader kq = tid>>5 reads words written by
    // tids kq*32..+31); same-wave LDS ops are program-ordered.
    float4 a2 = {0.f, 0.f, 0.f, 0.f};
    MAC32(hs, a2);
    *(float4*)&gred[rb][kq][g * 32 + jq * 4] = a2;
    __syncthreads();

    if (tid < 32) {   // reducer for hidden j = tid: 8 kq partials + Gc
      float4 s = gcr;
#pragma unroll
      for (int k2 = 0; k2 < 8; ++k2) {
        const float* gp = &gred[rb][k2][tid];
        s.x += gp[0]; s.y += gp[32]; s.z += gp[64]; s.w += gp[96];
      }
      const float ig = sigmoidf_(s.x), fg = sigmoidf_(s.y);
      const float gg = tanhf(s.z),     og = sigmoidf_(s.w);
      cst = fg * cst + ig * gg;
      const float hv = og * tanhf(cst);
      __hip_atomic_store(tht + (size_t)((t + 1) & 1) * BSZ * HID
                             + (size_t)b * HID + q * JB + tid,
                         (((u64)__float_as_uint(hv)) << 32) | (u64)(u32)(t + 1),
                         __ATOMIC_RELAXED, __HIP_MEMORY_SCOPE_AGENT);
    }
    // gred parity race-free: a t+2 overwrite of gred[rb] is preceded (in its
    // thread's program order) by poll(t+1) success, which requires our
    // reducer's publish(t+1), which follows its step-t gred[rb] reads.
  }

  // =================== epilogue: out[b] = ht @ Wf + bf ===================
  if (q == 0) {
    const u64* pp = tht + /*parity 0*/ (size_t)b * HID + tid;
    u64 pk;
    do {
      pk = __hip_atomic_load(pp, __ATOMIC_RELAXED, __HIP_MEMORY_SCOPE_AGENT);
    } while ((u32)pk != (u32)NSTEP);
    const float hv = __uint_as_float((u32)(pk >> 32));
    float prod = hv * Wf[tid];
#pragma unroll
    for (int mk = 1; mk < 64; mk <<= 1) prod += __shfl_xor(prod, mk);
    if (lane == 0) red[wv] = prod;
    __syncthreads();
    if (tid == 0) out[b] = red[0] + red[1] + red[2] + red[3] + bf[0];
  }
#undef MAC32
}

// ---------------------------------------------------------------------------
extern "C" void kernel_launch(void* const* d_in, const int* in_sizes, int n_in,
                              void* d_out, int out_size, void* d_ws, size_t ws_size,
                              hipStream_t stream)
{
  const float* x  = (const float*)d_in[0];
  const float* Wa = (const float*)d_in[1];
  // d_in[2] = ba: unused — constant along softmax axis, cancels exactly
  const float* Wi = (const float*)d_in[3];
  const float* Wh = (const float*)d_in[4];
  const float* bi = (const float*)d_in[5];
  const float* Wf = (const float*)d_in[6];
  const float* bf = (const float*)d_in[7];
  float* out = (float*)d_out;

  // ws: [0,128KB) tagged ht (2 parity bufs); [128KB,192KB) tagged ctx
  u64* tht  = (u64*)d_ws;
  u64* ctxT = (u64*)((char*)d_ws + 2 * BSZ * HID * sizeof(u64));

  hipLaunchKernelGGL(k_fused, dim3(BSZ * QB), dim3(256), 0, stream,
                     x, Wa, Wi, Wh, bi, Wf, bf, tht, ctxT, out);
}